// Round 1
// baseline (1212.629 us; speedup 1.0000x reference)
//
#include <hip/hip_runtime.h>

// Decoder step: attention (Bahdanau) + 2-layer LSTM + vocab projection.
// B=64, S=1024, V=32000, D=H=E=A=1024, L=2.
//
// d_out layout (floats): logits[64*32000] | h_new[2*64*1024] | c_new[2*64*1024] | attn_w[64*1024]
// ws layout  (floats): x[64*2048] @0 | q[64*1024] @131072 | score[64*1024] @196608 | part[] @262144
//   part region reused sequentially: qpart(8 splits) -> g0part(12) -> g1part(8) -> logpart(2)
//   max part = 2*64*32000 = 4,096,000 floats; total ws = 17.4 MB.
// bva is dropped: softmax(score + bva) == softmax(score), and score is not an output.

typedef __attribute__((ext_vector_type(8))) __bf16 bf16x8;
typedef __attribute__((ext_vector_type(4))) float f32x4;

__device__ __forceinline__ unsigned short f2bf(float f) {
  unsigned int u = __float_as_uint(f);
  u += 0x7FFFu + ((u >> 16) & 1u);   // RNE; inputs are finite
  return (unsigned short)(u >> 16);
}
__device__ __forceinline__ float sigm(float x) { return 1.0f / (1.0f + __expf(-x)); }

// x[b][0:1024] = emb[input_step[b]]
__global__ __launch_bounds__(256) void gather_k(const int* __restrict__ step,
                                                const float* __restrict__ emb,
                                                float* __restrict__ x) {
  int b = blockIdx.x, t = threadIdx.x;
  int row = step[b];
  f32x4 v = *(const f32x4*)(emb + (size_t)row * 1024 + t * 4);
  *(f32x4*)(x + (size_t)b * 2048 + t * 4) = v;
}

// Split-K skinny GEMM: part[z][m][n] = sum_{k in chunk z} Acat[m][k]*Bcat[n][k]
// M=64 fixed. BN=256 per block. A and B each given as 2 row-major segments
// (concat along K at kSplitA / kSplitB). 256 threads = 4 waves, wave w owns cols [64w,64w+64).
__global__ __launch_bounds__(256) void small_gemm(
    const float* __restrict__ A0, int lda0,
    const float* __restrict__ A1, int lda1, int kSplitA,
    const float* __restrict__ B0, int ldb0,
    const float* __restrict__ B1, int ldb1, int kSplitB,
    float* __restrict__ part, int N, int kChunk) {
  __shared__ unsigned short As[64 * 32];
  __shared__ unsigned short Bs[256 * 32];
  int tid = threadIdx.x;
  int n0 = blockIdx.x * 256;
  int k0 = blockIdx.y * kChunk;
  int wave = tid >> 6, lane = tid & 63, quad = lane >> 4, l15 = lane & 15;
  f32x4 acc[4][4] = {};
  for (int kb = k0; kb < k0 + kChunk; kb += 32) {
    const float* Ap; int ldA, kA;
    if (kb < kSplitA) { Ap = A0; ldA = lda0; kA = kb; }
    else              { Ap = A1; ldA = lda1; kA = kb - kSplitA; }
    const float* Bp; int ldB, kB;
    if (kb < kSplitB) { Bp = B0; ldB = ldb0; kB = kb; }
    else              { Bp = B1; ldB = ldb1; kB = kb - kSplitB; }
#pragma unroll
    for (int c = 0; c < 2; c++) {               // A: 64x32 fp32 -> bf16 LDS
      int f = c * 256 + tid;
      int row = f >> 3, colf = f & 7;
      f32x4 v = *(const f32x4*)(Ap + (size_t)row * ldA + kA + colf * 4);
      ushort4 p = make_ushort4(f2bf(v.x), f2bf(v.y), f2bf(v.z), f2bf(v.w));
      *(ushort4*)&As[row * 32 + colf * 4] = p;
    }
#pragma unroll
    for (int c = 0; c < 8; c++) {               // B: 256x32
      int f = c * 256 + tid;
      int row = f >> 3, colf = f & 7;
      f32x4 v = *(const f32x4*)(Bp + (size_t)(n0 + row) * ldB + kB + colf * 4);
      ushort4 p = make_ushort4(f2bf(v.x), f2bf(v.y), f2bf(v.z), f2bf(v.w));
      *(ushort4*)&Bs[row * 32 + colf * 4] = p;
    }
    __syncthreads();
    bf16x8 af[4], bfv[4];
#pragma unroll
    for (int rt = 0; rt < 4; rt++)
      af[rt] = *(const bf16x8*)&As[(16 * rt + l15) * 32 + quad * 8];
#pragma unroll
    for (int ct = 0; ct < 4; ct++)
      bfv[ct] = *(const bf16x8*)&Bs[(64 * wave + 16 * ct + l15) * 32 + quad * 8];
#pragma unroll
    for (int rt = 0; rt < 4; rt++)
#pragma unroll
      for (int ct = 0; ct < 4; ct++)
        acc[rt][ct] = __builtin_amdgcn_mfma_f32_16x16x32_bf16(af[rt], bfv[ct], acc[rt][ct], 0, 0, 0);
    __syncthreads();
  }
  size_t base = (size_t)blockIdx.y * 64 * (size_t)N;
#pragma unroll
  for (int rt = 0; rt < 4; rt++)
#pragma unroll
    for (int ct = 0; ct < 4; ct++)
#pragma unroll
      for (int r = 0; r < 4; r++) {
        int m = 16 * rt + 4 * quad + r;        // C/D layout: row = quad*4+reg
        int n = n0 + 64 * wave + 16 * ct + l15; // col = lane&15
        part[base + (size_t)m * N + n] = acc[rt][ct][r];
      }
}

// q[b][a] = ba_h[a] + sum over 8 k-splits
__global__ __launch_bounds__(256) void q_reduce(const float* __restrict__ qpart,
                                                const float* __restrict__ ba_h,
                                                float* __restrict__ q) {
  int idx = blockIdx.x * 256 + threadIdx.x;   // 65536
  int a = idx & 1023;
  float s = ba_h[a];
#pragma unroll
  for (int sp = 0; sp < 8; sp++) s += qpart[sp * 65536 + idx];
  q[idx] = s;
}

// k-projection GEMM (M=65536 x N=1024 x K=1024) with fused score epilogue.
// BM=128, BN=256, 512 threads = 8 waves (2 row x 4 col), each wave 64x64.
// score[bs] += sum_n va[n]*tanh(q[b][n] + k[bs][n] + ba_e[n])  (atomic across 4 N-tiles)
__global__ __launch_bounds__(512) void attn_gemm(
    const float* __restrict__ enc, const float* __restrict__ Wae,
    const float* __restrict__ q, const float* __restrict__ ba_e,
    const float* __restrict__ va, float* __restrict__ score) {
  __shared__ unsigned short As[128 * 32];
  __shared__ unsigned short Bs[256 * 32];
  __shared__ float red[128];
  int tid = threadIdx.x;
  int m0 = blockIdx.x * 128;   // bs
  int n0 = blockIdx.y * 256;   // a
  int wave = tid >> 6, lane = tid & 63, quad = lane >> 4, l15 = lane & 15;
  int wr = wave >> 2, wc = wave & 3;
  f32x4 acc[4][4] = {};
  for (int kb = 0; kb < 1024; kb += 32) {
#pragma unroll
    for (int c = 0; c < 2; c++) {               // A: 128x32
      int f = c * 512 + tid;
      int row = f >> 3, colf = f & 7;
      f32x4 v = *(const f32x4*)(enc + (size_t)(m0 + row) * 1024 + kb + colf * 4);
      ushort4 p = make_ushort4(f2bf(v.x), f2bf(v.y), f2bf(v.z), f2bf(v.w));
      *(ushort4*)&As[row * 32 + colf * 4] = p;
    }
#pragma unroll
    for (int c = 0; c < 4; c++) {               // B: 256x32
      int f = c * 512 + tid;
      int row = f >> 3, colf = f & 7;
      f32x4 v = *(const f32x4*)(Wae + (size_t)(n0 + row) * 1024 + kb + colf * 4);
      ushort4 p = make_ushort4(f2bf(v.x), f2bf(v.y), f2bf(v.z), f2bf(v.w));
      *(ushort4*)&Bs[row * 32 + colf * 4] = p;
    }
    __syncthreads();
    bf16x8 af[4], bfv[4];
#pragma unroll
    for (int rt = 0; rt < 4; rt++)
      af[rt] = *(const bf16x8*)&As[(64 * wr + 16 * rt + l15) * 32 + quad * 8];
#pragma unroll
    for (int ct = 0; ct < 4; ct++)
      bfv[ct] = *(const bf16x8*)&Bs[(64 * wc + 16 * ct + l15) * 32 + quad * 8];
#pragma unroll
    for (int rt = 0; rt < 4; rt++)
#pragma unroll
      for (int ct = 0; ct < 4; ct++)
        acc[rt][ct] = __builtin_amdgcn_mfma_f32_16x16x32_bf16(af[rt], bfv[ct], acc[rt][ct], 0, 0, 0);
    __syncthreads();
  }
  // fused score epilogue; whole block is inside one batch row b (128 | 1024)
  int b = m0 >> 10;
  if (tid < 128) red[tid] = 0.0f;
  __syncthreads();
  float qe[4], vv[4];
#pragma unroll
  for (int ct = 0; ct < 4; ct++) {
    int n = n0 + 64 * wc + 16 * ct + l15;
    qe[ct] = q[b * 1024 + n] + ba_e[n];
    vv[ct] = va[n];
  }
#pragma unroll
  for (int rt = 0; rt < 4; rt++)
#pragma unroll
    for (int r = 0; r < 4; r++) {
      float p = 0.0f;
#pragma unroll
      for (int ct = 0; ct < 4; ct++)
        p += vv[ct] * tanhf(qe[ct] + acc[rt][ct][r]);
      p += __shfl_xor(p, 1); p += __shfl_xor(p, 2);
      p += __shfl_xor(p, 4); p += __shfl_xor(p, 8);   // reduce the 16 col-lanes of this row
      if (l15 == 0) atomicAdd(&red[64 * wr + 16 * rt + 4 * quad + r], p);
    }
  __syncthreads();
  if (tid < 128) atomicAdd(&score[m0 + tid], red[tid]);
}

// attn_w = softmax(score) per batch row; 64 blocks x 256 threads, 4 vals/thread
__global__ __launch_bounds__(256) void softmax_k(const float* __restrict__ score,
                                                 float* __restrict__ attnw) {
  int b = blockIdx.x, tid = threadIdx.x;
  __shared__ float wred[4];
  float v[4];
  float mx = -1e30f;
#pragma unroll
  for (int i = 0; i < 4; i++) {
    v[i] = score[b * 1024 + tid + 256 * i];
    mx = fmaxf(mx, v[i]);
  }
  for (int off = 1; off < 64; off <<= 1) mx = fmaxf(mx, __shfl_xor(mx, off));
  int w = tid >> 6;
  if ((tid & 63) == 0) wred[w] = mx;
  __syncthreads();
  mx = fmaxf(fmaxf(wred[0], wred[1]), fmaxf(wred[2], wred[3]));
  float s = 0.0f;
#pragma unroll
  for (int i = 0; i < 4; i++) { v[i] = __expf(v[i] - mx); s += v[i]; }
  for (int off = 1; off < 64; off <<= 1) s += __shfl_xor(s, off);
  __syncthreads();
  if ((tid & 63) == 0) wred[w] = s;
  __syncthreads();
  s = wred[0] + wred[1] + wred[2] + wred[3];
  float inv = 1.0f / s;
#pragma unroll
  for (int i = 0; i < 4; i++) attnw[b * 1024 + tid + 256 * i] = v[i] * inv;
}

// x[b][1024+e] = sum_s attn_w[b][s] * enc[b][s][e]
__global__ __launch_bounds__(256) void context_k(const float* __restrict__ enc,
                                                 const float* __restrict__ attnw,
                                                 float* __restrict__ x) {
  __shared__ float w[1024];
  int b = blockIdx.y, e0 = blockIdx.x * 256, tid = threadIdx.x;
#pragma unroll
  for (int i = 0; i < 4; i++) w[tid + 256 * i] = attnw[b * 1024 + tid + 256 * i];
  __syncthreads();
  const float* ep = enc + (size_t)b * 1024 * 1024 + e0 + tid;
  float acc = 0.0f;
#pragma unroll 4
  for (int s = 0; s < 1024; s++) acc += w[s] * ep[(size_t)s * 1024];
  x[(size_t)b * 2048 + 1024 + e0 + tid] = acc;
}

// LSTM cell elementwise: reduce gate partials, apply activations
__global__ __launch_bounds__(256) void cell_k(const float* __restrict__ part, int nsplit,
                                              const float* __restrict__ bih,
                                              const float* __restrict__ bhh,
                                              const float* __restrict__ cin,
                                              float* __restrict__ hout,
                                              float* __restrict__ cout) {
  int idx = blockIdx.x * 256 + threadIdx.x;   // 65536
  int b = idx >> 10, h = idx & 1023;
  float gi = bih[h] + bhh[h];
  float gf = bih[1024 + h] + bhh[1024 + h];
  float gg = bih[2048 + h] + bhh[2048 + h];
  float go = bih[3072 + h] + bhh[3072 + h];
  const float* p = part + (size_t)b * 4096 + h;
  for (int sp = 0; sp < nsplit; sp++, p += 262144) {
    gi += p[0]; gf += p[1024]; gg += p[2048]; go += p[3072];
  }
  float c = sigm(gf) * cin[idx] + sigm(gi) * tanhf(gg);
  float hh = sigm(go) * tanhf(c);
  cout[idx] = c;
  hout[idx] = hh;
}

// logits[b][v] = bout[v] + part0 + part1
__global__ __launch_bounds__(256) void logits_reduce(const float* __restrict__ part,
                                                     const float* __restrict__ bout,
                                                     float* __restrict__ out) {
  int v = blockIdx.x * 256 + threadIdx.x;
  int b = blockIdx.y;
  size_t i = (size_t)b * 32000 + v;
  out[i] = bout[v] + part[i] + part[2048000 + i];
}

extern "C" void kernel_launch(void* const* d_in, const int* in_sizes, int n_in,
                              void* d_out, int out_size, void* d_ws, size_t ws_size,
                              hipStream_t stream) {
  const int*   input_step = (const int*)d_in[0];
  const float* h0   = (const float*)d_in[1];   // (2,64,1024)
  const float* c0   = (const float*)d_in[2];
  const float* enc  = (const float*)d_in[3];   // (64,1024,1024)
  const float* emb  = (const float*)d_in[4];   // (32000,1024)
  const float* Wa_h = (const float*)d_in[5];
  const float* ba_h = (const float*)d_in[6];
  const float* Wa_e = (const float*)d_in[7];
  const float* ba_e = (const float*)d_in[8];
  const float* va   = (const float*)d_in[9];
  // d_in[10] = bva: cancels in softmax, unused
  const float* Wih0 = (const float*)d_in[11];
  const float* Whh0 = (const float*)d_in[12];
  const float* bih0 = (const float*)d_in[13];
  const float* bhh0 = (const float*)d_in[14];
  const float* Wih1 = (const float*)d_in[15];
  const float* Whh1 = (const float*)d_in[16];
  const float* bih1 = (const float*)d_in[17];
  const float* bhh1 = (const float*)d_in[18];
  const float* Wout = (const float*)d_in[19];
  const float* bout = (const float*)d_in[20];

  float* out    = (float*)d_out;
  float* logits = out;                   // 64*32000
  float* h1o    = out + 2048000;         // h_new[0]
  float* h2o    = out + 2113536;         // h_new[1]
  float* c1o    = out + 2179072;         // c_new[0]
  float* c2o    = out + 2244608;         // c_new[1]
  float* attnw  = out + 2310144;         // attn_w

  float* ws    = (float*)d_ws;
  float* x     = ws;                     // 64*2048
  float* q     = ws + 131072;            // 64*1024
  float* score = ws + 196608;            // 64*1024
  float* part  = ws + 262144;            // reused partial region

  // 1. embedding gather into x[:, 0:1024]
  gather_k<<<64, 256, 0, stream>>>(input_step, emb, x);

  // 2. q = h0[1] @ Wa_h^T  (split-K partials, 8 splits of 128)
  small_gemm<<<dim3(4, 8), 256, 0, stream>>>(
      h0 + 65536, 1024, h0 + 65536, 1024, 1024,
      Wa_h, 1024, Wa_h, 1024, 1024,
      part, 1024, 128);
  q_reduce<<<256, 256, 0, stream>>>(part, ba_h, q);

  // 3. score accumulation (init to 0; bva dropped)
  hipMemsetAsync(score, 0, 65536 * sizeof(float), stream);
  attn_gemm<<<dim3(512, 4), 512, 0, stream>>>(enc, Wa_e, q, ba_e, va, score);

  // 4. softmax -> attn_w output
  softmax_k<<<64, 256, 0, stream>>>(score, attnw);

  // 5. context into x[:, 1024:2048]
  context_k<<<dim3(4, 64), 256, 0, stream>>>(enc, attnw, x);

  // 6. LSTM layer 0: gates = [x | h0[0]] @ [Wih0 | Whh0]^T  (12 splits of 256 over K=3072)
  small_gemm<<<dim3(16, 12), 256, 0, stream>>>(
      x, 2048, h0, 1024, 2048,
      Wih0, 2048, Whh0, 1024, 2048,
      part, 4096, 256);
  cell_k<<<256, 256, 0, stream>>>(part, 12, bih0, bhh0, c0, h1o, c1o);

  // 7. LSTM layer 1: gates = [h1 | h0[1]] @ [Wih1 | Whh1]^T  (8 splits of 256 over K=2048)
  small_gemm<<<dim3(16, 8), 256, 0, stream>>>(
      h1o, 1024, h0 + 65536, 1024, 1024,
      Wih1, 1024, Whh1, 1024, 1024,
      part, 4096, 256);
  cell_k<<<256, 256, 0, stream>>>(part, 8, bih1, bhh1, c0 + 65536, h2o, c2o);

  // 8. logits = h2 @ Wout^T + bout  (2 splits of 512 over K=1024)
  small_gemm<<<dim3(125, 2), 256, 0, stream>>>(
      h2o, 1024, h2o, 1024, 1024,
      Wout, 1024, Wout, 1024, 1024,
      part, 32000, 512);
  logits_reduce<<<dim3(125, 64), 256, 0, stream>>>(part, bout, logits);
}

// Round 3
// 854.365 us; speedup vs baseline: 1.4193x; 1.4193x over previous
//
#include <hip/hip_runtime.h>

// Decoder step: attention (Bahdanau) + 2-layer LSTM + vocab projection.
// B=64, S=1024, V=32000, D=H=E=A=1024, L=2.
//
// d_out (floats): logits[64*32000] | h_new[2*64*1024] | c_new[2*64*1024] | attn_w[64*1024]
// ws (floats), big path (needs 162,136,064 B):
//   x[64*2048]@0 | q@131072 | score@196608 | part@262144 (max 4,096,000)
//   ctxpart@4358144 (8*64*1024) | Wae_bf16@4882432 (1,048,576 ushorts) | enc_bf16@6979584
// bva dropped: softmax(score+bva)==softmax(score).
// R2 bug: cvt_bf_k(Wa_e) launched with n8=524288 (floats/2) instead of
// floats/8=131072 -> 12MB OOB read -> GPU fault. Fixed here.

typedef __attribute__((ext_vector_type(8))) __bf16 bf16x8;
typedef __attribute__((ext_vector_type(4))) __bf16 bf16x4v;
typedef __attribute__((ext_vector_type(4))) float f32x4;

#define GLOADLDS(g, l)                                                         \
  __builtin_amdgcn_global_load_lds(                                            \
      (const __attribute__((address_space(1))) unsigned int*)(g),              \
      (__attribute__((address_space(3))) unsigned int*)(l), 16, 0, 0)

__device__ __forceinline__ ushort4 cvt4(f32x4 v) {
  bf16x4v h = {(__bf16)v.x, (__bf16)v.y, (__bf16)v.z, (__bf16)v.w};  // RNE; native cvt_pk on gfx950
  union { bf16x4v h; ushort4 u; } c; c.h = h; return c.u;
}
__device__ __forceinline__ float bf2f(unsigned short u) {
  return __uint_as_float(((unsigned int)u) << 16);
}
__device__ __forceinline__ float sigm(float x) { return 1.0f / (1.0f + __expf(-x)); }

// fp32 -> bf16, 8 elements/thread; n8 = element_count / 8
__global__ __launch_bounds__(256) void cvt_bf_k(const float* __restrict__ in,
                                                unsigned short* __restrict__ out, int n8) {
  int i = blockIdx.x * 256 + threadIdx.x;
  if (i >= n8) return;
  const f32x4* p = (const f32x4*)in + 2 * (size_t)i;
  ushort4* o = (ushort4*)out + 2 * (size_t)i;
  f32x4 a = p[0], b = p[1];
  o[0] = cvt4(a);
  o[1] = cvt4(b);
}

// x[b][0:1024] = emb[input_step[b]]
__global__ __launch_bounds__(256) void gather_k(const int* __restrict__ step,
                                                const float* __restrict__ emb,
                                                float* __restrict__ x) {
  int b = blockIdx.x, t = threadIdx.x;
  int row = step[b];
  f32x4 v = *(const f32x4*)(emb + (size_t)row * 1024 + t * 4);
  *(f32x4*)(x + (size_t)b * 2048 + t * 4) = v;
}

// Split-K skinny GEMM, M=64, BN=256, fp32 in, bf16 staging via native casts.
__global__ __launch_bounds__(256) void small_gemm(
    const float* __restrict__ A0, int lda0,
    const float* __restrict__ A1, int lda1, int kSplitA,
    const float* __restrict__ B0, int ldb0,
    const float* __restrict__ B1, int ldb1, int kSplitB,
    float* __restrict__ part, int N, int kChunk) {
  __shared__ unsigned short As[64 * 32];
  __shared__ unsigned short Bs[256 * 32];
  int tid = threadIdx.x;
  int n0 = blockIdx.x * 256;
  int k0 = blockIdx.y * kChunk;
  int wave = tid >> 6, lane = tid & 63, quad = lane >> 4, l15 = lane & 15;
  f32x4 acc[4][4] = {};
  for (int kb = k0; kb < k0 + kChunk; kb += 32) {
    const float* Ap; int ldA, kA;
    if (kb < kSplitA) { Ap = A0; ldA = lda0; kA = kb; }
    else              { Ap = A1; ldA = lda1; kA = kb - kSplitA; }
    const float* Bp; int ldB, kB;
    if (kb < kSplitB) { Bp = B0; ldB = ldb0; kB = kb; }
    else              { Bp = B1; ldB = ldb1; kB = kb - kSplitB; }
#pragma unroll
    for (int c = 0; c < 2; c++) {               // A: 64x32
      int f = c * 256 + tid;
      int row = f >> 3, colf = f & 7;
      f32x4 v = *(const f32x4*)(Ap + (size_t)row * ldA + kA + colf * 4);
      *(ushort4*)&As[row * 32 + colf * 4] = cvt4(v);
    }
#pragma unroll
    for (int c = 0; c < 8; c++) {               // B: 256x32
      int f = c * 256 + tid;
      int row = f >> 3, colf = f & 7;
      f32x4 v = *(const f32x4*)(Bp + (size_t)(n0 + row) * ldB + kB + colf * 4);
      *(ushort4*)&Bs[row * 32 + colf * 4] = cvt4(v);
    }
    __syncthreads();
    bf16x8 af[4], bfv[4];
#pragma unroll
    for (int rt = 0; rt < 4; rt++)
      af[rt] = *(const bf16x8*)&As[(16 * rt + l15) * 32 + quad * 8];
#pragma unroll
    for (int ct = 0; ct < 4; ct++)
      bfv[ct] = *(const bf16x8*)&Bs[(64 * wave + 16 * ct + l15) * 32 + quad * 8];
#pragma unroll
    for (int rt = 0; rt < 4; rt++)
#pragma unroll
      for (int ct = 0; ct < 4; ct++)
        acc[rt][ct] = __builtin_amdgcn_mfma_f32_16x16x32_bf16(af[rt], bfv[ct], acc[rt][ct], 0, 0, 0);
    __syncthreads();
  }
  size_t base = (size_t)blockIdx.y * 64 * (size_t)N;
#pragma unroll
  for (int rt = 0; rt < 4; rt++)
#pragma unroll
    for (int ct = 0; ct < 4; ct++)
#pragma unroll
      for (int r = 0; r < 4; r++) {
        int m = 16 * rt + 4 * quad + r;
        int n = n0 + 64 * wave + 16 * ct + l15;
        part[base + (size_t)m * N + n] = acc[rt][ct][r];
      }
}

// q[b][a] = ba_h[a] + sum over 8 k-splits
__global__ __launch_bounds__(256) void q_reduce(const float* __restrict__ qpart,
                                                const float* __restrict__ ba_h,
                                                float* __restrict__ q) {
  int idx = blockIdx.x * 256 + threadIdx.x;
  int a = idx & 1023;
  float s = ba_h[a];
#pragma unroll
  for (int sp = 0; sp < 8; sp++) s += qpart[sp * 65536 + idx];
  q[idx] = s;
}

// bf16 attention GEMM: M=65536 N=1024 K=1024, BM=128 BN=256 BK=32.
// global_load_lds 16B direct staging; fused score epilogue.
// grid dim3(4 Ntiles, 512 Mtiles) — N-fastest so sibling N-tiles share A in L2/L3.
__global__ __launch_bounds__(512) void attn_gemm_bf(
    const unsigned short* __restrict__ encb, const unsigned short* __restrict__ Waeb,
    const float* __restrict__ q, const float* __restrict__ ba_e,
    const float* __restrict__ va, float* __restrict__ score) {
  __shared__ unsigned short As[128 * 32];
  __shared__ unsigned short Bs[256 * 32];
  __shared__ float red[128];
  int tid = threadIdx.x;
  int n0 = blockIdx.x * 256, m0 = blockIdx.y * 128;
  int wave = tid >> 6, lane = tid & 63, quad = lane >> 4, l15 = lane & 15;
  int wr = wave >> 2, wc = wave & 3;
  int lr = lane >> 2, lc = lane & 3;
  // staging: lane's 16B lands at LDS wavebase + lane*16
  const unsigned short* ga = encb + (size_t)(m0 + 16 * wave + lr) * 1024 + lc * 8;
  const unsigned short* gb = Waeb + (size_t)(n0 + 32 * wave + lr) * 1024 + lc * 8;
  unsigned short* lA  = &As[wave * 512];
  unsigned short* lB0 = &Bs[wave * 1024];
  unsigned short* lB1 = &Bs[wave * 1024 + 512];
  f32x4 acc[4][4] = {};
  for (int kb = 0; kb < 1024; kb += 32) {
    GLOADLDS(ga + kb, lA);
    GLOADLDS(gb + kb, lB0);
    GLOADLDS(gb + kb + 16 * 1024, lB1);
    __syncthreads();
    bf16x8 af[4], bfv[4];
#pragma unroll
    for (int rt = 0; rt < 4; rt++)
      af[rt] = *(const bf16x8*)&As[(64 * wr + 16 * rt + l15) * 32 + quad * 8];
#pragma unroll
    for (int ct = 0; ct < 4; ct++)
      bfv[ct] = *(const bf16x8*)&Bs[(64 * wc + 16 * ct + l15) * 32 + quad * 8];
#pragma unroll
    for (int rt = 0; rt < 4; rt++)
#pragma unroll
      for (int ct = 0; ct < 4; ct++)
        acc[rt][ct] = __builtin_amdgcn_mfma_f32_16x16x32_bf16(af[rt], bfv[ct], acc[rt][ct], 0, 0, 0);
    __syncthreads();
  }
  int b = m0 >> 10;
  if (tid < 128) red[tid] = 0.0f;
  __syncthreads();
  float qe[4], vv[4];
#pragma unroll
  for (int ct = 0; ct < 4; ct++) {
    int n = n0 + 64 * wc + 16 * ct + l15;
    qe[ct] = q[b * 1024 + n] + ba_e[n];
    vv[ct] = va[n];
  }
#pragma unroll
  for (int rt = 0; rt < 4; rt++)
#pragma unroll
    for (int r = 0; r < 4; r++) {
      float p = 0.0f;
#pragma unroll
      for (int ct = 0; ct < 4; ct++)
        p += vv[ct] * tanhf(qe[ct] + acc[rt][ct][r]);
      p += __shfl_xor(p, 1); p += __shfl_xor(p, 2);
      p += __shfl_xor(p, 4); p += __shfl_xor(p, 8);
      if (l15 == 0) atomicAdd(&red[64 * wr + 16 * rt + 4 * quad + r], p);
    }
  __syncthreads();
  if (tid < 128) atomicAdd(&score[m0 + tid], red[tid]);
}

// fallback fp32 attention GEMM (grid dim3(4,512), N-fastest)
__global__ __launch_bounds__(512) void attn_gemm_f32(
    const float* __restrict__ enc, const float* __restrict__ Wae,
    const float* __restrict__ q, const float* __restrict__ ba_e,
    const float* __restrict__ va, float* __restrict__ score) {
  __shared__ unsigned short As[128 * 32];
  __shared__ unsigned short Bs[256 * 32];
  __shared__ float red[128];
  int tid = threadIdx.x;
  int n0 = blockIdx.x * 256, m0 = blockIdx.y * 128;
  int wave = tid >> 6, lane = tid & 63, quad = lane >> 4, l15 = lane & 15;
  int wr = wave >> 2, wc = wave & 3;
  f32x4 acc[4][4] = {};
  for (int kb = 0; kb < 1024; kb += 32) {
#pragma unroll
    for (int c = 0; c < 2; c++) {
      int f = c * 512 + tid;
      int row = f >> 3, colf = f & 7;
      f32x4 v = *(const f32x4*)(enc + (size_t)(m0 + row) * 1024 + kb + colf * 4);
      *(ushort4*)&As[row * 32 + colf * 4] = cvt4(v);
    }
#pragma unroll
    for (int c = 0; c < 4; c++) {
      int f = c * 512 + tid;
      int row = f >> 3, colf = f & 7;
      f32x4 v = *(const f32x4*)(Wae + (size_t)(n0 + row) * 1024 + kb + colf * 4);
      *(ushort4*)&Bs[row * 32 + colf * 4] = cvt4(v);
    }
    __syncthreads();
    bf16x8 af[4], bfv[4];
#pragma unroll
    for (int rt = 0; rt < 4; rt++)
      af[rt] = *(const bf16x8*)&As[(64 * wr + 16 * rt + l15) * 32 + quad * 8];
#pragma unroll
    for (int ct = 0; ct < 4; ct++)
      bfv[ct] = *(const bf16x8*)&Bs[(64 * wc + 16 * ct + l15) * 32 + quad * 8];
#pragma unroll
    for (int rt = 0; rt < 4; rt++)
#pragma unroll
      for (int ct = 0; ct < 4; ct++)
        acc[rt][ct] = __builtin_amdgcn_mfma_f32_16x16x32_bf16(af[rt], bfv[ct], acc[rt][ct], 0, 0, 0);
    __syncthreads();
  }
  int b = m0 >> 10;
  if (tid < 128) red[tid] = 0.0f;
  __syncthreads();
  float qe[4], vv[4];
#pragma unroll
  for (int ct = 0; ct < 4; ct++) {
    int n = n0 + 64 * wc + 16 * ct + l15;
    qe[ct] = q[b * 1024 + n] + ba_e[n];
    vv[ct] = va[n];
  }
#pragma unroll
  for (int rt = 0; rt < 4; rt++)
#pragma unroll
    for (int r = 0; r < 4; r++) {
      float p = 0.0f;
#pragma unroll
      for (int ct = 0; ct < 4; ct++)
        p += vv[ct] * tanhf(qe[ct] + acc[rt][ct][r]);
      p += __shfl_xor(p, 1); p += __shfl_xor(p, 2);
      p += __shfl_xor(p, 4); p += __shfl_xor(p, 8);
      if (l15 == 0) atomicAdd(&red[64 * wr + 16 * rt + 4 * quad + r], p);
    }
  __syncthreads();
  if (tid < 128) atomicAdd(&score[m0 + tid], red[tid]);
}

__global__ __launch_bounds__(256) void softmax_k(const float* __restrict__ score,
                                                 float* __restrict__ attnw) {
  int b = blockIdx.x, tid = threadIdx.x;
  __shared__ float wred[4];
  float v[4];
  float mx = -1e30f;
#pragma unroll
  for (int i = 0; i < 4; i++) {
    v[i] = score[b * 1024 + tid + 256 * i];
    mx = fmaxf(mx, v[i]);
  }
  for (int off = 1; off < 64; off <<= 1) mx = fmaxf(mx, __shfl_xor(mx, off));
  int w = tid >> 6;
  if ((tid & 63) == 0) wred[w] = mx;
  __syncthreads();
  mx = fmaxf(fmaxf(wred[0], wred[1]), fmaxf(wred[2], wred[3]));
  float s = 0.0f;
#pragma unroll
  for (int i = 0; i < 4; i++) { v[i] = __expf(v[i] - mx); s += v[i]; }
  for (int off = 1; off < 64; off <<= 1) s += __shfl_xor(s, off);
  __syncthreads();
  if ((tid & 63) == 0) wred[w] = s;
  __syncthreads();
  s = wred[0] + wred[1] + wred[2] + wred[3];
  float inv = 1.0f / s;
#pragma unroll
  for (int i = 0; i < 4; i++) attnw[b * 1024 + tid + 256 * i] = v[i] * inv;
}

// context partial over s-chunks (bf16 enc): grid (64 b, 8 sc), thread owns 4 e
__global__ __launch_bounds__(256) void context_bf(const unsigned short* __restrict__ encb,
                                                  const float* __restrict__ attnw,
                                                  float* __restrict__ ctxpart) {
  int b = blockIdx.x, sc = blockIdx.y, tid = threadIdx.x;
  __shared__ float w[128];
  if (tid < 128) w[tid] = attnw[b * 1024 + sc * 128 + tid];
  __syncthreads();
  const unsigned short* ep = encb + (size_t)b * 1048576 + (size_t)sc * 128 * 1024 + tid * 4;
  f32x4 a0 = {}, a1 = {};
  for (int s = 0; s < 128; s += 2) {
    ushort4 u0 = *(const ushort4*)(ep + (size_t)s * 1024);
    ushort4 u1 = *(const ushort4*)(ep + (size_t)(s + 1) * 1024);
    float w0 = w[s], w1 = w[s + 1];
    a0.x += w0 * bf2f(u0.x); a0.y += w0 * bf2f(u0.y);
    a0.z += w0 * bf2f(u0.z); a0.w += w0 * bf2f(u0.w);
    a1.x += w1 * bf2f(u1.x); a1.y += w1 * bf2f(u1.y);
    a1.z += w1 * bf2f(u1.z); a1.w += w1 * bf2f(u1.w);
  }
  f32x4 r = a0 + a1;
  *(f32x4*)(ctxpart + ((size_t)sc * 64 + b) * 1024 + tid * 4) = r;
}

__global__ __launch_bounds__(256) void ctx_reduce(const float* __restrict__ ctxpart,
                                                  float* __restrict__ x) {
  int idx = blockIdx.x * 256 + threadIdx.x;   // 65536
  int b = idx >> 10, e = idx & 1023;
  float s = 0.0f;
#pragma unroll
  for (int sc = 0; sc < 8; sc++) s += ctxpart[((size_t)sc * 64 + b) * 1024 + e];
  x[(size_t)b * 2048 + 1024 + e] = s;
}

// fallback fp32 context
__global__ __launch_bounds__(256) void context_k(const float* __restrict__ enc,
                                                 const float* __restrict__ attnw,
                                                 float* __restrict__ x) {
  __shared__ float w[1024];
  int b = blockIdx.y, e0 = blockIdx.x * 256, tid = threadIdx.x;
#pragma unroll
  for (int i = 0; i < 4; i++) w[tid + 256 * i] = attnw[b * 1024 + tid + 256 * i];
  __syncthreads();
  const float* ep = enc + (size_t)b * 1024 * 1024 + e0 + tid;
  float acc = 0.0f;
#pragma unroll 4
  for (int s = 0; s < 1024; s++) acc += w[s] * ep[(size_t)s * 1024];
  x[(size_t)b * 2048 + 1024 + e0 + tid] = acc;
}

__global__ __launch_bounds__(256) void cell_k(const float* __restrict__ part, int nsplit,
                                              const float* __restrict__ bih,
                                              const float* __restrict__ bhh,
                                              const float* __restrict__ cin,
                                              float* __restrict__ hout,
                                              float* __restrict__ cout) {
  int idx = blockIdx.x * 256 + threadIdx.x;
  int b = idx >> 10, h = idx & 1023;
  float gi = bih[h] + bhh[h];
  float gf = bih[1024 + h] + bhh[1024 + h];
  float gg = bih[2048 + h] + bhh[2048 + h];
  float go = bih[3072 + h] + bhh[3072 + h];
  const float* p = part + (size_t)b * 4096 + h;
  for (int sp = 0; sp < nsplit; sp++, p += 262144) {
    gi += p[0]; gf += p[1024]; gg += p[2048]; go += p[3072];
  }
  float c = sigm(gf) * cin[idx] + sigm(gi) * tanhf(gg);
  float hh = sigm(go) * tanhf(c);
  cout[idx] = c;
  hout[idx] = hh;
}

__global__ __launch_bounds__(256) void logits_reduce(const float* __restrict__ part,
                                                     const float* __restrict__ bout,
                                                     float* __restrict__ out) {
  int v = blockIdx.x * 256 + threadIdx.x;
  int b = blockIdx.y;
  size_t i = (size_t)b * 32000 + v;
  out[i] = bout[v] + part[i] + part[2048000 + i];
}

extern "C" void kernel_launch(void* const* d_in, const int* in_sizes, int n_in,
                              void* d_out, int out_size, void* d_ws, size_t ws_size,
                              hipStream_t stream) {
  const int*   input_step = (const int*)d_in[0];
  const float* h0   = (const float*)d_in[1];
  const float* c0   = (const float*)d_in[2];
  const float* enc  = (const float*)d_in[3];
  const float* emb  = (const float*)d_in[4];
  const float* Wa_h = (const float*)d_in[5];
  const float* ba_h = (const float*)d_in[6];
  const float* Wa_e = (const float*)d_in[7];
  const float* ba_e = (const float*)d_in[8];
  const float* va   = (const float*)d_in[9];
  const float* Wih0 = (const float*)d_in[11];
  const float* Whh0 = (const float*)d_in[12];
  const float* bih0 = (const float*)d_in[13];
  const float* bhh0 = (const float*)d_in[14];
  const float* Wih1 = (const float*)d_in[15];
  const float* Whh1 = (const float*)d_in[16];
  const float* bih1 = (const float*)d_in[17];
  const float* bhh1 = (const float*)d_in[18];
  const float* Wout = (const float*)d_in[19];
  const float* bout = (const float*)d_in[20];

  float* out    = (float*)d_out;
  float* logits = out;
  float* h1o    = out + 2048000;
  float* h2o    = out + 2113536;
  float* c1o    = out + 2179072;
  float* c2o    = out + 2244608;
  float* attnw  = out + 2310144;

  float* ws      = (float*)d_ws;
  float* x       = ws;
  float* q       = ws + 131072;
  float* score   = ws + 196608;
  float* part    = ws + 262144;
  float* ctxpart = ws + 4358144;
  unsigned short* Waeb = (unsigned short*)(ws + 4882432);
  unsigned short* encb = (unsigned short*)(ws + 6979584);
  const bool big = ws_size >= 162136064ull;   // 40,534,016 floats

  gather_k<<<64, 256, 0, stream>>>(input_step, emb, x);

  // q = h0[1] @ Wa_h^T
  small_gemm<<<dim3(4, 8), 256, 0, stream>>>(
      h0 + 65536, 1024, h0 + 65536, 1024, 1024,
      Wa_h, 1024, Wa_h, 1024, 1024,
      part, 1024, 128);
  q_reduce<<<256, 256, 0, stream>>>(part, ba_h, q);

  hipMemsetAsync(score, 0, 65536 * sizeof(float), stream);

  if (big) {
    cvt_bf_k<<<512, 256, 0, stream>>>(Wa_e, Waeb, 131072);      // 1,048,576/8
    cvt_bf_k<<<32768, 256, 0, stream>>>(enc, encb, 8388608);    // 67,108,864/8
    attn_gemm_bf<<<dim3(4, 512), 512, 0, stream>>>(encb, Waeb, q, ba_e, va, score);
    softmax_k<<<64, 256, 0, stream>>>(score, attnw);
    context_bf<<<dim3(64, 8), 256, 0, stream>>>(encb, attnw, ctxpart);
    ctx_reduce<<<256, 256, 0, stream>>>(ctxpart, x);
  } else {
    attn_gemm_f32<<<dim3(4, 512), 512, 0, stream>>>(enc, Wa_e, q, ba_e, va, score);
    softmax_k<<<64, 256, 0, stream>>>(score, attnw);
    context_k<<<dim3(4, 64), 256, 0, stream>>>(enc, attnw, x);
  }

  // LSTM layer 0
  small_gemm<<<dim3(16, 12), 256, 0, stream>>>(
      x, 2048, h0, 1024, 2048,
      Wih0, 2048, Whh0, 1024, 2048,
      part, 4096, 256);
  cell_k<<<256, 256, 0, stream>>>(part, 12, bih0, bhh0, c0, h1o, c1o);

  // LSTM layer 1
  small_gemm<<<dim3(16, 8), 256, 0, stream>>>(
      h1o, 1024, h0 + 65536, 1024, 1024,
      Wih1, 1024, Whh1, 1024, 1024,
      part, 4096, 256);
  cell_k<<<256, 256, 0, stream>>>(part, 8, bih1, bhh1, c0 + 65536, h2o, c2o);

  // logits
  small_gemm<<<dim3(125, 2), 256, 0, stream>>>(
      h2o, 1024, h2o, 1024, 1024,
      Wout, 1024, Wout, 1024, 1024,
      part, 32000, 512);
  logits_reduce<<<dim3(125, 64), 256, 0, stream>>>(part, bout, logits);
}